// Round 8
// baseline (316.748 us; speedup 1.0000x reference)
//
#include <hip/hip_runtime.h>
#include <hip/hip_bf16.h>
#include <math.h>

#define B_SZ   1024
#define NROW   2048      // 2B
#define D_K    16384     // 128*128
#define SPLIT  8
#define KSEG   (D_K / SPLIT)   // 2048
#define NT64   32        // 2048/64
#define NPAIR64 528      // 32*33/2
#define NTILE  16
#define NPAIR  136
// fp8 rows scaled by 16 each => sim holds 256 * true_sim.
#define TEMP_SIM (2.0f / 256.0f)

typedef float f32x4 __attribute__((ext_vector_type(4)));
typedef long  i64;

typedef __attribute__((address_space(1))) unsigned int GU32;
typedef __attribute__((address_space(3))) unsigned int LU32;

__device__ __forceinline__ void async16(const void* g, void* l) {
  __builtin_amdgcn_global_load_lds((GU32*)(g), (LU32*)(l), 16, 0, 0);
}

// ---------------------------------------------------------------------------
// Kernel 1: per-row normalize -> fp8 e4m3 (x16) rn[2048][16384]; zero sim/rsum.
// ---------------------------------------------------------------------------
__global__ __launch_bounds__(512) void norm_kernel(
    const float* __restrict__ emb_i, const float* __restrict__ emb_j,
    unsigned char* __restrict__ rn, float* __restrict__ sim,
    float* __restrict__ rsum, unsigned int* __restrict__ cnt)
{
  const int b = blockIdx.x;
  const int t = threadIdx.x;
  const int c = t & 31;        // column group (4 cols)
  const int g = t >> 5;        // row group (8 rows), 0..15

  ((f32x4*)sim)[(size_t)b * 512 + t] = (f32x4){0.f, 0.f, 0.f, 0.f};
  if (b == 0) {
    for (int k = t; k < NROW; k += 512) rsum[k] = 0.f;
    if (t == 0) *cnt = 0u;
  }

  const float* src = (b < B_SZ) ? (emb_i + (size_t)b * D_K)
                                : (emb_j + (size_t)(b - B_SZ) * D_K);

  f32x4 vals[8];
  f32x4 ss = (f32x4){0.f, 0.f, 0.f, 0.f};
#pragma unroll
  for (int mm = 0; mm < 8; ++mm) {
    f32x4 v = *(const f32x4*)(src + (size_t)(g * 8 + mm) * 128 + c * 4);
    vals[mm] = v;
    ss += v * v;
  }

  __shared__ f32x4 part[16][32];
  part[g][c] = ss;
  __syncthreads();
  f32x4 css = part[0][c];
#pragma unroll
  for (int gg = 1; gg < 16; ++gg) css += part[gg][c];

  f32x4 mcn, colz2;
#pragma unroll
  for (int k = 0; k < 4; ++k) {
    mcn[k] = fmaxf(sqrtf(css[k]), 1e-12f);
    colz2[k] = css[k] / (mcn[k] * mcn[k]);
  }
  float s = colz2[0] + colz2[1] + colz2[2] + colz2[3];
#pragma unroll
  for (int off = 1; off < 64; off <<= 1) s += __shfl_xor(s, off);
  const float rowfac = fmaxf(sqrtf(0.5f * s), 1e-8f);

  f32x4 scale;
#pragma unroll
  for (int k = 0; k < 4; ++k) scale[k] = 16.0f / (mcn[k] * rowfac);

  unsigned char* dst = rn + (size_t)b * D_K;
#pragma unroll
  for (int mm = 0; mm < 8; ++mm) {
    f32x4 sv = vals[mm] * scale;
    int p = 0;
    p = __builtin_amdgcn_cvt_pk_fp8_f32(sv[0], sv[1], p, false);
    p = __builtin_amdgcn_cvt_pk_fp8_f32(sv[2], sv[3], p, true);
    *(int*)(dst + (size_t)(g * 8 + mm) * 128 + c * 4) = p;
  }
}

// ---------------------------------------------------------------------------
// Kernel 2: barrier-free wave-private GEMM. Each wave: one 64x64 upper tile
// (pair of 64-row panels), fp8 MFMA, BK=32, double-buffered private LDS,
// wave-local s_waitcnt vmcnt — NO __syncthreads in the K-loop.
// Grid (SPLIT, 132): XCD = linear%8 owns one K-segment (L2-resident).
// ---------------------------------------------------------------------------
__global__ __launch_bounds__(256) void gemm_sim_kernel(
    const unsigned char* __restrict__ rn, float* __restrict__ sim)
{
  const int t    = threadIdx.x;
  const int lane = t & 63;
  const int wave = t >> 6;
  const int quad = lane >> 4, col = lane & 15;

  // pair decode at 64-granularity
  int idx = blockIdx.y * 4 + wave, tI = 0, rem = NT64;
  while (idx >= rem) { idx -= rem; --rem; ++tI; }
  const int tJ = tI + idx;
  const bool diag = (tI == tJ);

  const int kBase = blockIdx.x * KSEG;

  // LDS: [buf][wave] private 64x32 panels for A and B
  __shared__ __align__(16) unsigned char LA[2][4][2048];
  __shared__ __align__(16) unsigned char LB[2][4][2048];

  // staging addresses: instr h covers rows h*32 + (lane>>1), chunk lane&1.
  // XOR swizzle: global 16B chunk (lane&1)^((row>>2)&1) -> LDS slot lane&1.
  const int srow = lane >> 1;
  const int c16  = (lane & 1) ^ ((srow >> 2) & 1);
  const unsigned char* aG0 = rn + (size_t)(tI * 64 + srow)      * D_K + kBase + c16 * 16;
  const unsigned char* aG1 = rn + (size_t)(tI * 64 + 32 + srow) * D_K + kBase + c16 * 16;
  const unsigned char* bG0 = rn + (size_t)(tJ * 64 + srow)      * D_K + kBase + c16 * 16;
  const unsigned char* bG1 = rn + (size_t)(tJ * 64 + 32 + srow) * D_K + kBase + c16 * 16;

  f32x4 acc[4][4];
#pragma unroll
  for (int mi = 0; mi < 4; ++mi)
#pragma unroll
    for (int ni = 0; ni < 4; ++ni)
      acc[mi][ni] = (f32x4){0.f, 0.f, 0.f, 0.f};

  // fragment read offset within a 64x32 panel (bank-conflict-free)
  const int c2 = (col >> 2) & 1;
  const int pw = ((quad >> 1) ^ c2) * 16 + (quad & 1) * 8;

  const int NIT = KSEG / 32;  // 64

  // prologue: stage iter 0 into buf 0
  {
    unsigned char* la = &LA[0][wave][lane * 16];
    unsigned char* lb = &LB[0][wave][lane * 16];
    async16(aG0, la);
    async16(aG1, la + 1024);
    async16(bG0, lb);
    async16(bG1, lb + 1024);
  }

  for (int it = 0; it < NIT; ++it) {
    const int buf = it & 1;
    __builtin_amdgcn_sched_barrier(0);
    if (it + 1 < NIT) {
      const int k1 = (it + 1) * 32;
      unsigned char* la = &LA[buf ^ 1][wave][lane * 16];
      unsigned char* lb = &LB[buf ^ 1][wave][lane * 16];
      async16(aG0 + k1, la);
      async16(aG1 + k1, la + 1024);
      async16(bG0 + k1, lb);
      async16(bG1 + k1, lb + 1024);
      __builtin_amdgcn_sched_barrier(0);
      __builtin_amdgcn_s_waitcnt(0x0F74);   // vmcnt(4): current buf ready
    } else {
      __builtin_amdgcn_sched_barrier(0);
      __builtin_amdgcn_s_waitcnt(0x0F70);   // vmcnt(0): last buf ready
    }
    __builtin_amdgcn_sched_barrier(0);

    const unsigned char* pa = &LA[buf][wave][0];
    const unsigned char* pb = &LB[buf][wave][0];
    i64 af[4], bf[4];
#pragma unroll
    for (int mi = 0; mi < 4; ++mi)
      af[mi] = *(const i64*)(pa + (mi * 16 + col) * 32 + pw);
#pragma unroll
    for (int ni = 0; ni < 4; ++ni)
      bf[ni] = *(const i64*)(pb + (ni * 16 + col) * 32 + pw);
#pragma unroll
    for (int mi = 0; mi < 4; ++mi)
#pragma unroll
      for (int ni = 0; ni < 4; ++ni)
        acc[mi][ni] = __builtin_amdgcn_mfma_f32_16x16x32_fp8_fp8(
            af[mi], bf[ni], acc[mi][ni], 0, 0, 0);
  }

  // epilogue: C/D layout col=lane&15, row=quad*4+reg. Diag: j>=i only.
  const int iB = tI * 64;
  const int jB = tJ * 64;
#pragma unroll
  for (int mi = 0; mi < 4; ++mi) {
#pragma unroll
    for (int reg = 0; reg < 4; ++reg) {
      const int i = iB + mi * 16 + quad * 4 + reg;
#pragma unroll
      for (int ni = 0; ni < 4; ++ni) {
        const int j = jB + ni * 16 + col;
        if (!diag || j >= i)
          atomicAdd(&sim[(size_t)i * NROW + j], acc[mi][ni][reg]);
      }
    }
  }
}

// ---------------------------------------------------------------------------
// Kernel 3: tile exp-sum (upper tiles, symmetric scatter) + fused finalize.
// ---------------------------------------------------------------------------
__global__ __launch_bounds__(256) void loss_tile_kernel(
    const float* __restrict__ sim, float* __restrict__ rsum,
    unsigned int* __restrict__ cnt, float* __restrict__ out)
{
  int idx = blockIdx.x, tI = 0, rem = NTILE;
  while (idx >= rem) { idx -= rem; --rem; ++tI; }
  const int tJ = tI + idx;
  const bool diag = (tI == tJ);

  const int t   = threadIdx.x;
  const int w   = t >> 6;
  const int l   = t & 63;
  const int hf  = l >> 5;
  const int sub = l & 31;
  const int jb  = tJ * 128 + sub * 4;

  float ca[4] = {0.f, 0.f, 0.f, 0.f};

#pragma unroll
  for (int step = 0; step < 16; ++step) {
    const int r  = w * 32 + step * 2 + hf;
    const int gi = tI * 128 + r;
    f32x4 v = *(const f32x4*)(sim + (size_t)gi * NROW + jb);
    float e[4];
#pragma unroll
    for (int k = 0; k < 4; ++k) {
      e[k] = __expf(TEMP_SIM * v[k]);
      if (diag && (jb + k <= gi)) e[k] = 0.f;
      ca[k] += e[k];
    }
    float rp = e[0] + e[1] + e[2] + e[3];
#pragma unroll
    for (int off = 1; off < 32; off <<= 1) rp += __shfl_xor(rp, off);
    if (sub == 0) atomicAdd(&rsum[gi], rp);
  }

  __shared__ float colacc[8][128];
#pragma unroll
  for (int k = 0; k < 4; ++k) colacc[w * 2 + hf][sub * 4 + k] = ca[k];
  __syncthreads();
  if (t < 128) {
    float s = 0.f;
#pragma unroll
    for (int q = 0; q < 8; ++q) s += colacc[q][t];
    atomicAdd(&rsum[tJ * 128 + t], s);
  }

  __syncthreads();
  __shared__ bool last;
  if (t == 0) {
    __threadfence();
    last = (atomicAdd(cnt, 1u) == NPAIR - 1);
  }
  __syncthreads();
  if (!last) return;

  float s = 0.f;
  for (int i = t; i < NROW; i += 256) {
    const int jp = (i < B_SZ) ? i + B_SZ : i - B_SZ;
    const float pos = (jp >= i) ? sim[(size_t)i * NROW + jp]
                                : sim[(size_t)jp * NROW + i];
    const float rs = atomicAdd(&rsum[i], 0.f);
    s += logf(rs) - TEMP_SIM * pos;
  }
#pragma unroll
  for (int off = 1; off < 64; off <<= 1) s += __shfl_xor(s, off);
  __shared__ float r[4];
  if ((t & 63) == 0) r[t >> 6] = s;
  __syncthreads();
  if (t == 0) out[0] = (r[0] + r[1] + r[2] + r[3]) * (1.0f / NROW);
}

extern "C" void kernel_launch(void* const* d_in, const int* in_sizes, int n_in,
                              void* d_out, int out_size, void* d_ws, size_t ws_size,
                              hipStream_t stream) {
  const float* emb_i = (const float*)d_in[0];
  const float* emb_j = (const float*)d_in[1];
  float* out = (float*)d_out;

  char* ws = (char*)d_ws;
  unsigned char* rn = (unsigned char*)ws;                 // 32 MB (fp8)
  float* sim  = (float*)(ws + (size_t)NROW * D_K);        // 16 MB
  float* rsum = sim + (size_t)NROW * NROW;                // 8 KB
  unsigned int* cnt = (unsigned int*)(rsum + NROW);

  norm_kernel<<<dim3(NROW), dim3(512), 0, stream>>>(emb_i, emb_j, rn, sim, rsum, cnt);
  gemm_sim_kernel<<<dim3(SPLIT, NPAIR64 / 4), dim3(256), 0, stream>>>(rn, sim);
  loss_tile_kernel<<<dim3(NPAIR), dim3(256), 0, stream>>>(sim, rsum, cnt, out);
}

// Round 9
// 259.376 us; speedup vs baseline: 1.2212x; 1.2212x over previous
//
#include <hip/hip_runtime.h>
#include <hip/hip_bf16.h>
#include <math.h>

#define B_SZ   1024
#define NROW   2048      // 2B
#define D_K    16384     // 128*128
#define SPLIT  8
#define KSEG   (D_K / SPLIT)   // 2048
#define NTILE  16
#define NPAIR  136
// fp8 rows scaled by 16 each => sim holds 256 * true_sim.
#define TEMP_SIM (2.0f / 256.0f)

typedef float f32x4 __attribute__((ext_vector_type(4)));
typedef long  i64;

typedef __attribute__((address_space(1))) unsigned int GU32;
typedef __attribute__((address_space(3))) unsigned int LU32;

__device__ __forceinline__ void async16(const void* g, void* l) {
  __builtin_amdgcn_global_load_lds((GU32*)(g), (LU32*)(l), 16, 0, 0);
}

// ---------------------------------------------------------------------------
// Kernel 1: per-row normalize -> fp8 e4m3 (x16) rn[2048][16384]; zero sim/rsum.
// ---------------------------------------------------------------------------
__global__ __launch_bounds__(512) void norm_kernel(
    const float* __restrict__ emb_i, const float* __restrict__ emb_j,
    unsigned char* __restrict__ rn, float* __restrict__ sim,
    float* __restrict__ rsum, unsigned int* __restrict__ cnt)
{
  const int b = blockIdx.x;
  const int t = threadIdx.x;
  const int c = t & 31;        // column group (4 cols)
  const int g = t >> 5;        // row group (8 rows), 0..15

  ((f32x4*)sim)[(size_t)b * 512 + t] = (f32x4){0.f, 0.f, 0.f, 0.f};
  if (b == 0) {
    for (int k = t; k < NROW; k += 512) rsum[k] = 0.f;
    if (t == 0) *cnt = 0u;
  }

  const float* src = (b < B_SZ) ? (emb_i + (size_t)b * D_K)
                                : (emb_j + (size_t)(b - B_SZ) * D_K);

  f32x4 vals[8];
  f32x4 ss = (f32x4){0.f, 0.f, 0.f, 0.f};
#pragma unroll
  for (int mm = 0; mm < 8; ++mm) {
    f32x4 v = *(const f32x4*)(src + (size_t)(g * 8 + mm) * 128 + c * 4);
    vals[mm] = v;
    ss += v * v;
  }

  __shared__ f32x4 part[16][32];
  part[g][c] = ss;
  __syncthreads();
  f32x4 css = part[0][c];
#pragma unroll
  for (int gg = 1; gg < 16; ++gg) css += part[gg][c];

  f32x4 mcn, colz2;
#pragma unroll
  for (int k = 0; k < 4; ++k) {
    mcn[k] = fmaxf(sqrtf(css[k]), 1e-12f);
    colz2[k] = css[k] / (mcn[k] * mcn[k]);
  }
  float s = colz2[0] + colz2[1] + colz2[2] + colz2[3];
#pragma unroll
  for (int off = 1; off < 64; off <<= 1) s += __shfl_xor(s, off);
  const float rowfac = fmaxf(sqrtf(0.5f * s), 1e-8f);

  f32x4 scale;
#pragma unroll
  for (int k = 0; k < 4; ++k) scale[k] = 16.0f / (mcn[k] * rowfac);

  unsigned char* dst = rn + (size_t)b * D_K;
#pragma unroll
  for (int mm = 0; mm < 8; ++mm) {
    f32x4 sv = vals[mm] * scale;
    int p = 0;
    p = __builtin_amdgcn_cvt_pk_fp8_f32(sv[0], sv[1], p, false);
    p = __builtin_amdgcn_cvt_pk_fp8_f32(sv[2], sv[3], p, true);
    *(int*)(dst + (size_t)(g * 8 + mm) * 128 + c * 4) = p;
  }
}

// ---------------------------------------------------------------------------
// Kernel 2: sim(upper) += rn @ rn^T. fp8 MFMA, 128x128 tile, BK=128:
// 16 barrier-pairs per block (64 MFMA/wave per drain). Row-XOR chunk swizzle
// keeps fragment ds_read_b64 at ~2-way banking while staging stays
// lane-contiguous for global_load_lds. Grid (SPLIT, 136): XCD = linear%8
// owns one K-segment -> 4 MB L2-resident.
// ---------------------------------------------------------------------------
__global__ __launch_bounds__(256) void gemm_sim_kernel(
    const unsigned char* __restrict__ rn, float* __restrict__ sim)
{
  int idx = blockIdx.y, tI = 0, rem = NTILE;
  while (idx >= rem) { idx -= rem; --rem; ++tI; }
  const int tJ = tI + idx;
  const bool diag = (tI == tJ);

  const int kBase = blockIdx.x * KSEG;
  const int t    = threadIdx.x;
  const int lane = t & 63;
  const int wave = t >> 6;
  const int wm = wave >> 1, wn = wave & 1;
  const int quad = lane >> 4, col = lane & 15;

  __shared__ __align__(16) unsigned char As[128 * 128];  // 16 KB
  __shared__ __align__(16) unsigned char Bs[128 * 128];  // 16 KB

  // staging: instr i stages rows 32i..32i+31. thread t -> row 32i+(t>>3),
  // global 16B chunk gc=(t&7)^(row&7) stored at LDS chunk t&7 (off i*4096+t*16).
  const int srow = t >> 3;
  const int gc   = (t & 7) ^ (srow & 7);
  const unsigned char* aGb = rn + (size_t)(tI * 128 + srow) * D_K + kBase + gc * 16;
  const unsigned char* bGb = rn + (size_t)(tJ * 128 + srow) * D_K + kBase + gc * 16;

  f32x4 acc[4][4];
#pragma unroll
  for (int mi = 0; mi < 4; ++mi)
#pragma unroll
    for (int ni = 0; ni < 4; ++ni)
      acc[mi][ni] = (f32x4){0.f, 0.f, 0.f, 0.f};

  for (int k0 = 0; k0 < KSEG; k0 += 128) {
    __syncthreads();
#pragma unroll
    for (int i = 0; i < 4; ++i) {
      async16(aGb + (size_t)(32 * i) * D_K + k0, &As[i * 4096 + t * 16]);
      async16(bGb + (size_t)(32 * i) * D_K + k0, &Bs[i * 4096 + t * 16]);
    }
    __syncthreads();

#pragma unroll
    for (int h = 0; h < 4; ++h) {
      // lane wants global k-bytes [32h + quad*8, +8) of its row:
      // chunk g = 2h + (quad>>1), stored at LDS chunk g ^ (row&7), row&7 = col&7
      const int off = ((2 * h + (quad >> 1)) ^ (col & 7)) * 16 + (quad & 1) * 8;
      i64 af[4], bf[4];
#pragma unroll
      for (int mi = 0; mi < 4; ++mi)
        af[mi] = *(const i64*)(&As[(wm * 64 + mi * 16 + col) * 128 + off]);
#pragma unroll
      for (int ni = 0; ni < 4; ++ni)
        bf[ni] = *(const i64*)(&Bs[(wn * 64 + ni * 16 + col) * 128 + off]);
#pragma unroll
      for (int mi = 0; mi < 4; ++mi)
#pragma unroll
        for (int ni = 0; ni < 4; ++ni)
          acc[mi][ni] = __builtin_amdgcn_mfma_f32_16x16x32_fp8_fp8(
              af[mi], bf[ni], acc[mi][ni], 0, 0, 0);
    }
  }

  // C/D layout: col=lane&15, row=quad*4+reg. Diag tiles: only j >= i stored.
  const int iB = tI * 128 + wm * 64;
  const int jB = tJ * 128 + wn * 64;
#pragma unroll
  for (int mi = 0; mi < 4; ++mi) {
#pragma unroll
    for (int reg = 0; reg < 4; ++reg) {
      const int i = iB + mi * 16 + quad * 4 + reg;
#pragma unroll
      for (int ni = 0; ni < 4; ++ni) {
        const int j = jB + ni * 16 + col;
        if (!diag || j >= i)
          atomicAdd(&sim[(size_t)i * NROW + j], acc[mi][ni][reg]);
      }
    }
  }
}

// ---------------------------------------------------------------------------
// Kernel 3: tile exp-sum (upper tiles, symmetric scatter) + fused finalize.
// ---------------------------------------------------------------------------
__global__ __launch_bounds__(256) void loss_tile_kernel(
    const float* __restrict__ sim, float* __restrict__ rsum,
    unsigned int* __restrict__ cnt, float* __restrict__ out)
{
  int idx = blockIdx.x, tI = 0, rem = NTILE;
  while (idx >= rem) { idx -= rem; --rem; ++tI; }
  const int tJ = tI + idx;
  const bool diag = (tI == tJ);

  const int t   = threadIdx.x;
  const int w   = t >> 6;
  const int l   = t & 63;
  const int hf  = l >> 5;
  const int sub = l & 31;
  const int jb  = tJ * 128 + sub * 4;

  float ca[4] = {0.f, 0.f, 0.f, 0.f};

#pragma unroll
  for (int step = 0; step < 16; ++step) {
    const int r  = w * 32 + step * 2 + hf;
    const int gi = tI * 128 + r;
    f32x4 v = *(const f32x4*)(sim + (size_t)gi * NROW + jb);
    float e[4];
#pragma unroll
    for (int k = 0; k < 4; ++k) {
      e[k] = __expf(TEMP_SIM * v[k]);
      if (diag && (jb + k <= gi)) e[k] = 0.f;
      ca[k] += e[k];
    }
    float rp = e[0] + e[1] + e[2] + e[3];
#pragma unroll
    for (int off = 1; off < 32; off <<= 1) rp += __shfl_xor(rp, off);
    if (sub == 0) atomicAdd(&rsum[gi], rp);
  }

  __shared__ float colacc[8][128];
#pragma unroll
  for (int k = 0; k < 4; ++k) colacc[w * 2 + hf][sub * 4 + k] = ca[k];
  __syncthreads();
  if (t < 128) {
    float s = 0.f;
#pragma unroll
    for (int q = 0; q < 8; ++q) s += colacc[q][t];
    atomicAdd(&rsum[tJ * 128 + t], s);
  }

  __syncthreads();
  __shared__ bool last;
  if (t == 0) {
    __threadfence();
    last = (atomicAdd(cnt, 1u) == NPAIR - 1);
  }
  __syncthreads();
  if (!last) return;

  float s = 0.f;
  for (int i = t; i < NROW; i += 256) {
    const int jp = (i < B_SZ) ? i + B_SZ : i - B_SZ;
    const float pos = (jp >= i) ? sim[(size_t)i * NROW + jp]
                                : sim[(size_t)jp * NROW + i];
    const float rs = atomicAdd(&rsum[i], 0.f);
    s += logf(rs) - TEMP_SIM * pos;
  }
#pragma unroll
  for (int off = 1; off < 64; off <<= 1) s += __shfl_xor(s, off);
  __shared__ float r[4];
  if ((t & 63) == 0) r[t >> 6] = s;
  __syncthreads();
  if (t == 0) out[0] = (r[0] + r[1] + r[2] + r[3]) * (1.0f / NROW);
}

extern "C" void kernel_launch(void* const* d_in, const int* in_sizes, int n_in,
                              void* d_out, int out_size, void* d_ws, size_t ws_size,
                              hipStream_t stream) {
  const float* emb_i = (const float*)d_in[0];
  const float* emb_j = (const float*)d_in[1];
  float* out = (float*)d_out;

  char* ws = (char*)d_ws;
  unsigned char* rn = (unsigned char*)ws;                 // 32 MB (fp8)
  float* sim  = (float*)(ws + (size_t)NROW * D_K);        // 16 MB
  float* rsum = sim + (size_t)NROW * NROW;                // 8 KB
  unsigned int* cnt = (unsigned int*)(rsum + NROW);

  norm_kernel<<<dim3(NROW), dim3(512), 0, stream>>>(emb_i, emb_j, rn, sim, rsum, cnt);
  gemm_sim_kernel<<<dim3(SPLIT, NPAIR), dim3(256), 0, stream>>>(rn, sim);
  loss_tile_kernel<<<dim3(NPAIR), dim3(256), 0, stream>>>(sim, rsum, cnt, out);
}